// Round 8
// baseline (1708.726 us; speedup 1.0000x reference)
//
#include <hip/hip_runtime.h>
#include <hip/hip_bf16.h>
#include <math.h>

#define BATCH 32
#define TSEQ 1024
#define DMODEL 1024
#define KEXP 8
#define FFFN 4096
#define EEMB 64
#define RHID 128
#define NSTAGE 5
#define NVIEW 4

typedef float f32x4 __attribute__((ext_vector_type(4)));
typedef __bf16 bf16x8 __attribute__((ext_vector_type(8)));
typedef unsigned short u16x8 __attribute__((ext_vector_type(8)));

#define AS1C(p) ((const __attribute__((address_space(1))) unsigned int*)(p))
#define AS3(p)  ((__attribute__((address_space(3))) unsigned int*)(p))

__device__ __forceinline__ unsigned short f32_to_bf16_rne(float f) {
    union { float f; unsigned int u; } v; v.f = f;
    unsigned int u = v.u;
    unsigned int r = u + 0x7FFFu + ((u >> 16) & 1u);
    return (unsigned short)(r >> 16);
}

__device__ __forceinline__ u16x8 pack8(f32x4 a, f32x4 b) {
    u16x8 r;
    r[0] = f32_to_bf16_rne(a[0]); r[1] = f32_to_bf16_rne(a[1]);
    r[2] = f32_to_bf16_rne(a[2]); r[3] = f32_to_bf16_rne(a[3]);
    r[4] = f32_to_bf16_rne(b[0]); r[5] = f32_to_bf16_rne(b[1]);
    r[6] = f32_to_bf16_rne(b[2]); r[7] = f32_to_bf16_rne(b[3]);
    return r;
}

__device__ void resolve_ids_r8(const int* __restrict__ raw, int* __restrict__ out, int hi) {
    bool is64 = true;
    for (int i = 1; i < 32; i += 2) is64 = is64 && (raw[i] == 0);
    for (int i = 0; i < 32; i += 2) is64 = is64 && (raw[i] >= 0 && raw[i] < hi);
    for (int b = 0; b < BATCH; ++b) {
        int v = is64 ? raw[2 * b] : raw[b];
        v = v < 0 ? 0 : (v >= hi ? hi - 1 : v);
        out[b] = v;
    }
}

// ---------------- router: fp64 exact, ALL OUTPUTS F32 ----------------
__global__ void router_r8(const int* __restrict__ stage_ids,
                          const int* __restrict__ view_ids,
                          const float* __restrict__ stage_emb,
                          const float* __restrict__ view_emb,
                          const float* __restrict__ rw1,
                          const float* __restrict__ rb1,
                          const float* __restrict__ rw2,
                          const float* __restrict__ rb2,
                          float* __restrict__ out_probs,
                          float* __restrict__ out_sel,
                          float* __restrict__ out_loss,
                          int* __restrict__ sel_ws)
{
    __shared__ int sids[BATCH], vids[BATCH];
    __shared__ double z[2 * EEMB];
    __shared__ double h[RHID];
    __shared__ double lg[KEXP];
    __shared__ double Psum[KEXP];
    __shared__ int fcount[KEXP];
    const int t = threadIdx.x;
    if (t == 0) {
        resolve_ids_r8(stage_ids, sids, NSTAGE);
        resolve_ids_r8(view_ids, vids, NVIEW);
    }
    if (t < KEXP) { Psum[t] = 0.0; fcount[t] = 0; }
    __syncthreads();

    for (int b = 0; b < BATCH; ++b) {
        const int sid = sids[b], vid = vids[b];
        if (t < EEMB) z[t] = (double)stage_emb[sid * EEMB + t];
        else          z[t] = (double)view_emb[vid * EEMB + (t - EEMB)];
        __syncthreads();
        double acc = (double)rb1[t];
        for (int i = 0; i < 2 * EEMB; ++i) acc += z[i] * (double)rw1[i * RHID + t];
        h[t] = fmax(acc, 0.0);
        __syncthreads();
        if (t < KEXP) {
            double a = (double)rb2[t];
            for (int i = 0; i < RHID; ++i) a += h[i] * (double)rw2[i * KEXP + t];
            lg[t] = a;
        }
        __syncthreads();
        if (t == 0) {
            double mx = lg[0]; int am = 0;
            for (int k = 1; k < KEXP; ++k) if (lg[k] > mx) { mx = lg[k]; am = k; }
            double p[KEXP]; double den = 0.0;
            for (int k = 0; k < KEXP; ++k) { p[k] = exp(lg[k] - mx); den += p[k]; }
            for (int k = 0; k < KEXP; ++k) {
                double pk = p[k] / den;
                out_probs[b * KEXP + k] = (float)pk;
                Psum[k] += pk;
            }
            out_sel[b] = (float)am;
            sel_ws[b] = am;
            fcount[am] += 1;
        }
        __syncthreads();
    }
    if (t == 0) {
        double loss = 0.0;
        for (int k = 0; k < KEXP; ++k)
            loss += ((double)fcount[k] / (double)BATCH) * (Psum[k] / (double)BATCH);
        out_loss[0] = (float)((double)KEXP * loss);
    }
}

// ---------------- MFMA expert GEMM, in-kernel staging ----------------
#define BM 128
#define BN 128
#define BK 32

template<int MODE, int ADT, int OBF>
__global__ __launch_bounds__(256) void ffn_mfma_r8(
    const void* __restrict__ Aall_,
    const float* __restrict__ Ball,
    const float* __restrict__ biasAll,
    void* __restrict__ OutV,
    const int* __restrict__ sel, int g0,
    int M, int N, int K)
{
    const int bz = blockIdx.z;
    int e = sel[g0 + bz];
    e = e < 0 ? 0 : (e >= KEXP ? KEXP - 1 : e);
    const float* B32  = Ball + (size_t)e * (size_t)K * N;
    const float* bias = biasAll + (size_t)e * N;

    __shared__ __align__(16) unsigned short As[BM][BK];
    __shared__ __align__(16) unsigned short Bs[BN][BK];
    __shared__ __align__(16) float Braw[BK][BN + 4];

    const int tid  = threadIdx.x;
    const int wave = tid >> 6;
    const int lane = tid & 63;
    const int wr = wave >> 1;
    const int wc = wave & 1;
    const int fr = lane & 15;
    const int fq = lane >> 4;
    const int brow = blockIdx.y * BM;
    const int bcol = blockIdx.x * BN;

    const int a_row = tid >> 1;
    const int a_kh  = (tid & 1) * 16;
    const int srow = lane >> 2;
    const int scol = (lane & 3) * 8;
    const int b_kr = tid >> 3;
    const int b_nc = (tid & 7) * 16;
    const int t_n  = tid >> 1;
    const int t_kh = (tid & 1) * 16;

    const float* A32 = (const float*)Aall_ + (size_t)bz * M * K;
    const unsigned short* A16 = (const unsigned short*)Aall_ + (size_t)bz * M * K;

    const f32x4 zero = {0.f, 0.f, 0.f, 0.f};
    f32x4 acc[4][4];
    #pragma unroll
    for (int m = 0; m < 4; ++m)
        #pragma unroll
        for (int n = 0; n < 4; ++n) acc[m][n] = zero;

    for (int k0 = 0; k0 < K; k0 += BK) {
        if (ADT == 0) {
            const float* g = A32 + (size_t)(brow + a_row) * K + (k0 + a_kh);
            f32x4 v0 = *(const f32x4*)(g);
            f32x4 v1 = *(const f32x4*)(g + 4);
            f32x4 v2 = *(const f32x4*)(g + 8);
            f32x4 v3 = *(const f32x4*)(g + 12);
            *(u16x8*)&As[a_row][a_kh]     = pack8(v0, v1);
            *(u16x8*)&As[a_row][a_kh + 8] = pack8(v2, v3);
        } else {
            #pragma unroll
            for (int i = 0; i < 2; ++i) {
                const int c = wave * 2 + i;
                const unsigned short* gA = A16 + (size_t)(brow + c * 16 + srow) * K + (k0 + scol);
                __builtin_amdgcn_global_load_lds(AS1C(gA), AS3(&As[c * 16][0]), 16, 0, 0);
            }
        }
        {
            const float* g = B32 + (size_t)(k0 + b_kr) * N + (bcol + b_nc);
            *(f32x4*)&Braw[b_kr][b_nc]      = *(const f32x4*)(g);
            *(f32x4*)&Braw[b_kr][b_nc + 4]  = *(const f32x4*)(g + 4);
            *(f32x4*)&Braw[b_kr][b_nc + 8]  = *(const f32x4*)(g + 8);
            *(f32x4*)&Braw[b_kr][b_nc + 12] = *(const f32x4*)(g + 12);
        }
        __syncthreads();

        {
            float tv[16];
            #pragma unroll
            for (int j = 0; j < 16; ++j) tv[j] = Braw[t_kh + j][t_n];
            u16x8 blo, bhi;
            #pragma unroll
            for (int j = 0; j < 8; ++j) { blo[j] = f32_to_bf16_rne(tv[j]); bhi[j] = f32_to_bf16_rne(tv[j + 8]); }
            *(u16x8*)&Bs[t_n][t_kh]     = blo;
            *(u16x8*)&Bs[t_n][t_kh + 8] = bhi;
        }
        __syncthreads();

        bf16x8 af[4], bfr[4];
        #pragma unroll
        for (int m = 0; m < 4; ++m)
            af[m] = *(const bf16x8*)(&As[wr * 64 + m * 16 + fr][fq * 8]);
        #pragma unroll
        for (int n = 0; n < 4; ++n)
            bfr[n] = *(const bf16x8*)(&Bs[wc * 64 + n * 16 + fr][fq * 8]);

        #pragma unroll
        for (int m = 0; m < 4; ++m)
            #pragma unroll
            for (int n = 0; n < 4; ++n)
                acc[m][n] = __builtin_amdgcn_mfma_f32_16x16x32_bf16(af[m], bfr[n], acc[m][n], 0, 0, 0);

        __syncthreads();
    }

    #pragma unroll
    for (int m = 0; m < 4; ++m) {
        #pragma unroll
        for (int n = 0; n < 4; ++n) {
            #pragma unroll
            for (int r = 0; r < 4; ++r) {
                const int row = brow + wr * 64 + m * 16 + fq * 4 + r;
                const int col = bcol + wc * 64 + n * 16 + fr;
                float v = acc[m][n][r] + bias[col];
                if (MODE == 0) v = 0.5f * v * (1.0f + erff(v * 0.70710678118654752f));
                const size_t idx = (size_t)bz * M * N + (size_t)row * N + col;
                if (OBF) ((unsigned short*)OutV)[idx] = f32_to_bf16_rne(v);
                else     ((float*)OutV)[idx] = v;
            }
        }
    }
}

extern "C" void kernel_launch(void* const* d_in, const int* in_sizes, int n_in,
                              void* d_out, int out_size, void* d_ws, size_t ws_size,
                              hipStream_t stream)
{
    const float* x         = (const float*)d_in[0];
    const int*   stage_ids = (const int*)d_in[1];
    const int*   view_ids  = (const int*)d_in[2];
    const float* stage_emb = (const float*)d_in[3];
    const float* view_emb  = (const float*)d_in[4];
    const float* rw1       = (const float*)d_in[5];
    const float* rb1       = (const float*)d_in[6];
    const float* rw2       = (const float*)d_in[7];
    const float* rb2       = (const float*)d_in[8];
    const float* w1        = (const float*)d_in[9];
    const float* b1        = (const float*)d_in[10];
    const float* w2        = (const float*)d_in[11];
    const float* b2        = (const float*)d_in[12];

    float* out_f = (float*)d_out;   // f32 output (confirmed: out_npz 124.6MB = f32)
    const size_t OUT_ELEMS = (size_t)BATCH * TSEQ * DMODEL;

    char* ws = (char*)d_ws;
    int* sel_ws            = (int*)ws;
    unsigned short* h_bf16 = (unsigned short*)(ws + 4096);

    int grp = 1;
    {
        const size_t avail = ws_size > 4096 ? ws_size - 4096 : 0;
        for (int g = 32; g >= 1; g >>= 1) {
            if ((size_t)g * TSEQ * FFFN * 2 <= avail) { grp = g; break; }
        }
    }

    router_r8<<<1, RHID, 0, stream>>>(stage_ids, view_ids, stage_emb, view_emb,
        rw1, rb1, rw2, rb2,
        out_f + OUT_ELEMS,
        out_f + OUT_ELEMS + BATCH * KEXP,
        out_f + OUT_ELEMS + BATCH * KEXP + BATCH,
        sel_ws);

    for (int g0 = 0; g0 < BATCH; g0 += grp) {
        ffn_mfma_r8<0, 0, 1><<<dim3(FFFN / BN, TSEQ / BM, grp), 256, 0, stream>>>(
            (const void*)(x + (size_t)g0 * TSEQ * DMODEL), w1, b1,
            (void*)h_bf16, sel_ws, g0, TSEQ, FFFN, DMODEL);
        ffn_mfma_r8<1, 1, 0><<<dim3(DMODEL / BN, TSEQ / BM, grp), 256, 0, stream>>>(
            (const void*)h_bf16, w2, b2,
            (void*)(out_f + (size_t)g0 * TSEQ * DMODEL), sel_ws, g0, TSEQ, DMODEL, FFFN);
    }
}

// Round 9
// 1195.559 us; speedup vs baseline: 1.4292x; 1.4292x over previous
//
#include <hip/hip_runtime.h>
#include <hip/hip_bf16.h>
#include <math.h>

#define BATCH 32
#define TSEQ 1024
#define DMODEL 1024
#define KEXP 8
#define FFFN 4096
#define EEMB 64
#define RHID 128
#define NSTAGE 5
#define NVIEW 4

typedef float f32x4 __attribute__((ext_vector_type(4)));
typedef __bf16 bf16x8 __attribute__((ext_vector_type(8)));

#define AS1C(p) ((const __attribute__((address_space(1))) unsigned int*)(p))
#define AS3(p)  ((__attribute__((address_space(3))) unsigned int*)(p))

__device__ __forceinline__ unsigned short f32_to_bf16_rne(float f) {
    union { float f; unsigned int u; } v; v.f = f;
    unsigned int u = v.u;
    unsigned int r = u + 0x7FFFu + ((u >> 16) & 1u);
    return (unsigned short)(r >> 16);
}

__device__ void resolve_ids_r9(const int* __restrict__ raw, int* __restrict__ out, int hi) {
    bool is64 = true;
    for (int i = 1; i < 32; i += 2) is64 = is64 && (raw[i] == 0);
    for (int i = 0; i < 32; i += 2) is64 = is64 && (raw[i] >= 0 && raw[i] < hi);
    for (int b = 0; b < BATCH; ++b) {
        int v = is64 ? raw[2 * b] : raw[b];
        v = v < 0 ? 0 : (v >= hi ? hi - 1 : v);
        out[b] = v;
    }
}

// ---------------- router: fp64 exact, f32 outputs ----------------
__global__ void router_r9(const int* __restrict__ stage_ids,
                          const int* __restrict__ view_ids,
                          const float* __restrict__ stage_emb,
                          const float* __restrict__ view_emb,
                          const float* __restrict__ rw1,
                          const float* __restrict__ rb1,
                          const float* __restrict__ rw2,
                          const float* __restrict__ rb2,
                          float* __restrict__ out_probs,
                          float* __restrict__ out_sel,
                          float* __restrict__ out_loss,
                          int* __restrict__ sel_ws)
{
    __shared__ int sids[BATCH], vids[BATCH];
    __shared__ double z[2 * EEMB];
    __shared__ double h[RHID];
    __shared__ double lg[KEXP];
    __shared__ double Psum[KEXP];
    __shared__ int fcount[KEXP];
    const int t = threadIdx.x;
    if (t == 0) {
        resolve_ids_r9(stage_ids, sids, NSTAGE);
        resolve_ids_r9(view_ids, vids, NVIEW);
    }
    if (t < KEXP) { Psum[t] = 0.0; fcount[t] = 0; }
    __syncthreads();

    for (int b = 0; b < BATCH; ++b) {
        const int sid = sids[b], vid = vids[b];
        if (t < EEMB) z[t] = (double)stage_emb[sid * EEMB + t];
        else          z[t] = (double)view_emb[vid * EEMB + (t - EEMB)];
        __syncthreads();
        double acc = (double)rb1[t];
        for (int i = 0; i < 2 * EEMB; ++i) acc += z[i] * (double)rw1[i * RHID + t];
        h[t] = fmax(acc, 0.0);
        __syncthreads();
        if (t < KEXP) {
            double a = (double)rb2[t];
            for (int i = 0; i < RHID; ++i) a += h[i] * (double)rw2[i * KEXP + t];
            lg[t] = a;
        }
        __syncthreads();
        if (t == 0) {
            double mx = lg[0]; int am = 0;
            for (int k = 1; k < KEXP; ++k) if (lg[k] > mx) { mx = lg[k]; am = k; }
            double p[KEXP]; double den = 0.0;
            for (int k = 0; k < KEXP; ++k) { p[k] = exp(lg[k] - mx); den += p[k]; }
            for (int k = 0; k < KEXP; ++k) {
                double pk = p[k] / den;
                out_probs[b * KEXP + k] = (float)pk;
                Psum[k] += pk;
            }
            out_sel[b] = (float)am;
            sel_ws[b] = am;
            fcount[am] += 1;
        }
        __syncthreads();
    }
    if (t == 0) {
        double loss = 0.0;
        for (int k = 0; k < KEXP; ++k)
            loss += ((double)fcount[k] / (double)BATCH) * (Psum[k] / (double)BATCH);
        out_loss[0] = (float)((double)KEXP * loss);
    }
}

// ---------------- prep: f32 -> bf16 straight convert (x) ----------------
__global__ void cvt_f32_bf16_r9(const float* __restrict__ src,
                                unsigned short* __restrict__ dst, size_t n)
{
    size_t i = (size_t)blockIdx.x * blockDim.x + threadIdx.x;
    size_t stride = (size_t)gridDim.x * blockDim.x;
    for (size_t j = i * 4; j < n; j += stride * 4) {
        float4 v = *(const float4*)(src + j);
        ushort4 o;
        o.x = f32_to_bf16_rne(v.x); o.y = f32_to_bf16_rne(v.y);
        o.z = f32_to_bf16_rne(v.z); o.w = f32_to_bf16_rne(v.w);
        *(ushort4*)(dst + j) = o;
    }
}

// ------ prep: tiled transpose+convert src[e][R][C] f32 -> dst[e][C][R] bf16 ------
__global__ void transpose_f32_bf16_r9(const float* __restrict__ src,
                                      unsigned short* __restrict__ dst,
                                      int R, int C)
{
    __shared__ float tile[32][33];
    const int e = blockIdx.z;
    const float* s = src + (size_t)e * R * C;
    unsigned short* d = dst + (size_t)e * R * C;
    const int c0 = blockIdx.x * 32, r0 = blockIdx.y * 32;
    const int tx = threadIdx.x, ty = threadIdx.y; // (32, 8)
    #pragma unroll
    for (int i = 0; i < 32; i += 8)
        tile[ty + i][tx] = s[(size_t)(r0 + ty + i) * C + (c0 + tx)];
    __syncthreads();
    #pragma unroll
    for (int i = 0; i < 32; i += 8)
        d[(size_t)(c0 + ty + i) * R + (r0 + tx)] = f32_to_bf16_rne(tile[tx][ty + i]);
}

// ---------------- m97-structure MFMA GEMM: C = A @ B^T (+bias [,gelu]) ----------------
// A: [z][M][K] bf16; BT: [KEXP][N][K] bf16 (pre-transposed weights); staging via
// global_load_lds width=16. Verified on HW in round 8 (fragment + epilogue maps).
#define BM 128
#define BN 128
#define BK 32

template<int MODE, int OBF>  // MODE 0: gelu(acc+bias); 1: acc+bias. OBF: 1 bf16 out, 0 f32 out
__global__ __launch_bounds__(256) void gemm_bt_r9(
    const unsigned short* __restrict__ Aall,
    const unsigned short* __restrict__ BTall,
    const float* __restrict__ biasAll,
    void* __restrict__ OutV,
    const int* __restrict__ sel, int g0,
    int M, int N, int K)
{
    const int bz = blockIdx.z;
    int e = sel[g0 + bz];
    e = e < 0 ? 0 : (e >= KEXP ? KEXP - 1 : e);
    const unsigned short* A  = Aall + (size_t)bz * M * K;
    const unsigned short* BT = BTall + (size_t)e * (size_t)N * K;
    const float* bias = biasAll + (size_t)e * N;

    __shared__ __align__(16) unsigned short As[BM][BK]; // 8 KB
    __shared__ __align__(16) unsigned short Bs[BN][BK]; // 8 KB

    const int tid  = threadIdx.x;
    const int wave = tid >> 6;
    const int lane = tid & 63;
    const int wr = wave >> 1;
    const int wc = wave & 1;
    const int fr = lane & 15;
    const int fq = lane >> 4;
    const int brow = blockIdx.y * BM;
    const int bcol = blockIdx.x * BN;

    const int srow = lane >> 2;        // 16 rows per 1KB chunk
    const int scol = (lane & 3) * 8;   // 4 lanes x 16B per row

    const f32x4 zero = {0.f, 0.f, 0.f, 0.f};
    f32x4 acc[4][4];
    #pragma unroll
    for (int m = 0; m < 4; ++m)
        #pragma unroll
        for (int n = 0; n < 4; ++n) acc[m][n] = zero;

    for (int k0 = 0; k0 < K; k0 += BK) {
        #pragma unroll
        for (int i = 0; i < 2; ++i) {
            const int c = wave * 2 + i;
            const unsigned short* gA = A + (size_t)(brow + c * 16 + srow) * K + (k0 + scol);
            __builtin_amdgcn_global_load_lds(AS1C(gA), AS3(&As[c * 16][0]), 16, 0, 0);
        }
        #pragma unroll
        for (int i = 0; i < 2; ++i) {
            const int c = wave * 2 + i;
            const unsigned short* gB = BT + (size_t)(bcol + c * 16 + srow) * K + (k0 + scol);
            __builtin_amdgcn_global_load_lds(AS1C(gB), AS3(&Bs[c * 16][0]), 16, 0, 0);
        }
        __syncthreads();

        bf16x8 af[4], bfr[4];
        #pragma unroll
        for (int m = 0; m < 4; ++m)
            af[m] = *(const bf16x8*)(&As[wr * 64 + m * 16 + fr][fq * 8]);
        #pragma unroll
        for (int n = 0; n < 4; ++n)
            bfr[n] = *(const bf16x8*)(&Bs[wc * 64 + n * 16 + fr][fq * 8]);

        #pragma unroll
        for (int m = 0; m < 4; ++m)
            #pragma unroll
            for (int n = 0; n < 4; ++n)
                acc[m][n] = __builtin_amdgcn_mfma_f32_16x16x32_bf16(af[m], bfr[n], acc[m][n], 0, 0, 0);

        __syncthreads();
    }

    // epilogue: C/D col=lane&15, row=(lane>>4)*4+reg  [HW-verified round 8]
    #pragma unroll
    for (int m = 0; m < 4; ++m) {
        #pragma unroll
        for (int n = 0; n < 4; ++n) {
            #pragma unroll
            for (int r = 0; r < 4; ++r) {
                const int row = brow + wr * 64 + m * 16 + fq * 4 + r;
                const int col = bcol + wc * 64 + n * 16 + fr;
                float v = acc[m][n][r] + bias[col];
                if (MODE == 0) v = 0.5f * v * (1.0f + erff(v * 0.70710678118654752f));
                const size_t idx = (size_t)bz * M * N + (size_t)row * N + col;
                if (OBF) ((unsigned short*)OutV)[idx] = f32_to_bf16_rne(v);
                else     ((float*)OutV)[idx] = v;
            }
        }
    }
}

extern "C" void kernel_launch(void* const* d_in, const int* in_sizes, int n_in,
                              void* d_out, int out_size, void* d_ws, size_t ws_size,
                              hipStream_t stream)
{
    const float* x         = (const float*)d_in[0];
    const int*   stage_ids = (const int*)d_in[1];
    const int*   view_ids  = (const int*)d_in[2];
    const float* stage_emb = (const float*)d_in[3];
    const float* view_emb  = (const float*)d_in[4];
    const float* rw1       = (const float*)d_in[5];
    const float* rb1       = (const float*)d_in[6];
    const float* rw2       = (const float*)d_in[7];
    const float* rb2       = (const float*)d_in[8];
    const float* w1        = (const float*)d_in[9];
    const float* b1        = (const float*)d_in[10];
    const float* w2        = (const float*)d_in[11];
    const float* b2        = (const float*)d_in[12];

    float* out_f = (float*)d_out;   // f32 output (confirmed round 8)
    const size_t OUT_ELEMS = (size_t)BATCH * TSEQ * DMODEL;

    // ws layout: [4KB hdr][x_bf 64MB][w1T 64MB][w2T 64MB][h grp*8MB]
    const size_t MB64 = 67108864ull;
    char* ws = (char*)d_ws;
    int* sel_ws            = (int*)ws;
    unsigned short* x_bf   = (unsigned short*)(ws + 4096);
    unsigned short* w1T    = (unsigned short*)(ws + 4096 + MB64);
    unsigned short* w2T    = (unsigned short*)(ws + 4096 + 2 * MB64);
    unsigned short* h_bf   = (unsigned short*)(ws + 4096 + 3 * MB64);

    // adaptive h-group size (round-8 run proved ws_size >= 256MB+4KB -> grp >= 8)
    int grp = 1;
    {
        const size_t base = 4096 + 3 * MB64;
        const size_t avail = ws_size > base ? ws_size - base : 0;
        for (int g = 32; g >= 1; g >>= 1) {
            if ((size_t)g * TSEQ * FFFN * 2 <= avail) { grp = g; break; }
        }
    }

    router_r9<<<1, RHID, 0, stream>>>(stage_ids, view_ids, stage_emb, view_emb,
        rw1, rb1, rw2, rb2,
        out_f + OUT_ELEMS,
        out_f + OUT_ELEMS + BATCH * KEXP,
        out_f + OUT_ELEMS + BATCH * KEXP + BATCH,
        sel_ws);

    // prep: x -> bf16; w1 [8][D][F] -> w1T [8][F][D]; w2 [8][F][D] -> w2T [8][D][F]
    cvt_f32_bf16_r9<<<2048, 256, 0, stream>>>(x, x_bf, (size_t)BATCH * TSEQ * DMODEL);
    dim3 tb(32, 8);
    transpose_f32_bf16_r9<<<dim3(FFFN / 32, DMODEL / 32, KEXP), tb, 0, stream>>>(w1, w1T, DMODEL, FFFN);
    transpose_f32_bf16_r9<<<dim3(DMODEL / 32, FFFN / 32, KEXP), tb, 0, stream>>>(w2, w2T, FFFN, DMODEL);

    for (int g0 = 0; g0 < BATCH; g0 += grp) {
        // h = gelu(x @ w1[e]^T + b1[e]) : M=1024, N=4096, K=1024 -> bf16
        gemm_bt_r9<0, 1><<<dim3(FFFN / BN, TSEQ / BM, grp), 256, 0, stream>>>(
            x_bf + (size_t)g0 * TSEQ * DMODEL, w1T, b1,
            (void*)h_bf, sel_ws, g0, TSEQ, FFFN, DMODEL);
        // out = h @ w2[e]^T + b2[e]     : M=1024, N=1024, K=4096 -> f32
        gemm_bt_r9<1, 0><<<dim3(DMODEL / BN, TSEQ / BM, grp), 256, 0, stream>>>(
            h_bf, w2T, b2,
            (void*)(out_f + (size_t)g0 * TSEQ * DMODEL), sel_ws, g0, TSEQ, DMODEL, FFFN);
    }
}

// Round 10
// 1050.584 us; speedup vs baseline: 1.6265x; 1.1380x over previous
//
#include <hip/hip_runtime.h>
#include <hip/hip_bf16.h>
#include <math.h>

#define BATCH 32
#define TSEQ 1024
#define DMODEL 1024
#define KEXP 8
#define FFFN 4096
#define EEMB 64
#define RHID 128
#define NSTAGE 5
#define NVIEW 4

typedef float f32x4 __attribute__((ext_vector_type(4)));
typedef __bf16 bf16x8 __attribute__((ext_vector_type(8)));

#define AS1C(p) ((const __attribute__((address_space(1))) unsigned int*)(p))
#define AS3(p)  ((__attribute__((address_space(3))) unsigned int*)(p))

__device__ __forceinline__ unsigned short f32_to_bf16_rne(float f) {
    union { float f; unsigned int u; } v; v.f = f;
    unsigned int u = v.u;
    unsigned int r = u + 0x7FFFu + ((u >> 16) & 1u);
    return (unsigned short)(r >> 16);
}

__device__ void resolve_ids_r10(const int* __restrict__ raw, int* __restrict__ out, int hi) {
    bool is64 = true;
    for (int i = 1; i < 32; i += 2) is64 = is64 && (raw[i] == 0);
    for (int i = 0; i < 32; i += 2) is64 = is64 && (raw[i] >= 0 && raw[i] < hi);
    for (int b = 0; b < BATCH; ++b) {
        int v = is64 ? raw[2 * b] : raw[b];
        v = v < 0 ? 0 : (v >= hi ? hi - 1 : v);
        out[b] = v;
    }
}

// ---------------- router: fp64 exact, f32 outputs ----------------
__global__ void router_r10(const int* __restrict__ stage_ids,
                           const int* __restrict__ view_ids,
                           const float* __restrict__ stage_emb,
                           const float* __restrict__ view_emb,
                           const float* __restrict__ rw1,
                           const float* __restrict__ rb1,
                           const float* __restrict__ rw2,
                           const float* __restrict__ rb2,
                           float* __restrict__ out_probs,
                           float* __restrict__ out_sel,
                           float* __restrict__ out_loss,
                           int* __restrict__ sel_ws)
{
    __shared__ int sids[BATCH], vids[BATCH];
    __shared__ double z[2 * EEMB];
    __shared__ double h[RHID];
    __shared__ double lg[KEXP];
    __shared__ double Psum[KEXP];
    __shared__ int fcount[KEXP];
    const int t = threadIdx.x;
    if (t == 0) {
        resolve_ids_r10(stage_ids, sids, NSTAGE);
        resolve_ids_r10(view_ids, vids, NVIEW);
    }
    if (t < KEXP) { Psum[t] = 0.0; fcount[t] = 0; }
    __syncthreads();

    for (int b = 0; b < BATCH; ++b) {
        const int sid = sids[b], vid = vids[b];
        if (t < EEMB) z[t] = (double)stage_emb[sid * EEMB + t];
        else          z[t] = (double)view_emb[vid * EEMB + (t - EEMB)];
        __syncthreads();
        double acc = (double)rb1[t];
        for (int i = 0; i < 2 * EEMB; ++i) acc += z[i] * (double)rw1[i * RHID + t];
        h[t] = fmax(acc, 0.0);
        __syncthreads();
        if (t < KEXP) {
            double a = (double)rb2[t];
            for (int i = 0; i < RHID; ++i) a += h[i] * (double)rw2[i * KEXP + t];
            lg[t] = a;
        }
        __syncthreads();
        if (t == 0) {
            double mx = lg[0]; int am = 0;
            for (int k = 1; k < KEXP; ++k) if (lg[k] > mx) { mx = lg[k]; am = k; }
            double p[KEXP]; double den = 0.0;
            for (int k = 0; k < KEXP; ++k) { p[k] = exp(lg[k] - mx); den += p[k]; }
            for (int k = 0; k < KEXP; ++k) {
                double pk = p[k] / den;
                out_probs[b * KEXP + k] = (float)pk;
                Psum[k] += pk;
            }
            out_sel[b] = (float)am;
            sel_ws[b] = am;
            fcount[am] += 1;
        }
        __syncthreads();
    }
    if (t == 0) {
        double loss = 0.0;
        for (int k = 0; k < KEXP; ++k)
            loss += ((double)fcount[k] / (double)BATCH) * (Psum[k] / (double)BATCH);
        out_loss[0] = (float)((double)KEXP * loss);
    }
}

// ---------------- prep: f32 -> bf16 convert (x) ----------------
__global__ void cvt_f32_bf16_r10(const float* __restrict__ src,
                                 unsigned short* __restrict__ dst, size_t n)
{
    size_t i = (size_t)blockIdx.x * blockDim.x + threadIdx.x;
    size_t stride = (size_t)gridDim.x * blockDim.x;
    for (size_t j = i * 4; j < n; j += stride * 4) {
        float4 v = *(const float4*)(src + j);
        ushort4 o;
        o.x = f32_to_bf16_rne(v.x); o.y = f32_to_bf16_rne(v.y);
        o.z = f32_to_bf16_rne(v.z); o.w = f32_to_bf16_rne(v.w);
        *(ushort4*)(dst + j) = o;
    }
}

// ------ prep: tiled transpose+convert src[e][R][C] f32 -> dst[e][C][R] bf16 ------
__global__ void transpose_f32_bf16_r10(const float* __restrict__ src,
                                       unsigned short* __restrict__ dst,
                                       int R, int C)
{
    __shared__ float tile[32][33];
    const int e = blockIdx.z;
    const float* s = src + (size_t)e * R * C;
    unsigned short* d = dst + (size_t)e * R * C;
    const int c0 = blockIdx.x * 32, r0 = blockIdx.y * 32;
    const int tx = threadIdx.x, ty = threadIdx.y; // (32, 8)
    #pragma unroll
    for (int i = 0; i < 32; i += 8)
        tile[ty + i][tx] = s[(size_t)(r0 + ty + i) * C + (c0 + tx)];
    __syncthreads();
    #pragma unroll
    for (int i = 0; i < 32; i += 8)
        d[(size_t)(c0 + ty + i) * R + (r0 + tx)] = f32_to_bf16_rne(tile[tx][ty + i]);
}

// ================= 256x256 / BK=64 / 8-wave counted-vmcnt MFMA GEMM =================
// C = A @ BT^T (+bias [,gelu]).  A: [z][M][K] bf16, BT: [KEXP][N][K] bf16.
// LDS 128KB = 2 buf x (A 32KB + B 32KB); rows 128B; T2 chunk-XOR swizzle
// (linear global_load_lds dest + pre-swizzled source + swizzled ds_read, rule #21).
// Pipeline: depth-2 prefetch, counted vmcnt(8) (T4), 2 barriers/K-tile, setprio (T5).

template<int MODE, int OBF>  // MODE 0: gelu(acc+bias); 1: acc+bias. OBF: 1 bf16 out, 0 f32 out
__global__ __launch_bounds__(512, 2) void gemm_bt_r10(
    const unsigned short* __restrict__ Aall,
    const unsigned short* __restrict__ BTall,
    const float* __restrict__ biasAll,
    void* __restrict__ OutV,
    const int* __restrict__ sel, int g0,
    int M, int N, int K)
{
    const int bz = blockIdx.z;
    int e = sel[g0 + bz];
    e = e < 0 ? 0 : (e >= KEXP ? KEXP - 1 : e);
    const unsigned short* A  = Aall + (size_t)bz * M * K;
    const unsigned short* BT = BTall + (size_t)e * (size_t)N * K;
    const float* bias = biasAll + (size_t)e * N;

    __shared__ __align__(16) unsigned short lds[65536];   // 128 KB
    char* Lc = (char*)lds;

    const int tid  = threadIdx.x;
    const int lane = tid & 63;
    const int wave = tid >> 6;     // 0..7
    const int wr = wave >> 2;      // 0..1 : wave row (128 rows each)
    const int wc = wave & 3;       // 0..3 : wave col (64 cols each)
    const int fr = lane & 15;
    const int fq = lane >> 4;
    const int swz = fr & 7;        // read-side row-XOR (row&7 == fr&7)

    const int brow = blockIdx.y * 256;
    const int bcol = blockIdx.x * 256;

    // staging geometry: sweep s covers rows [s*64, s*64+64); wave covers 8 rows;
    // lane>>3 = row-within-wave (== row&7); source chunk pre-swizzled.
    const int srow8 = wave * 8 + (lane >> 3);
    const int scolh = ((lane & 7) ^ (lane >> 3)) * 8;   // halfword offset in 64-hw row

    const int NT = K >> 6;

    const f32x4 zero = {0.f, 0.f, 0.f, 0.f};
    f32x4 acc[8][4];
    #pragma unroll
    for (int m = 0; m < 8; ++m)
        #pragma unroll
        for (int n = 0; n < 4; ++n) acc[m][n] = zero;

    auto STAGE = [&](int buf, int kt) {
        const int kh = kt * 64;
        #pragma unroll
        for (int s = 0; s < 4; ++s) {
            const unsigned short* g = A + (size_t)(brow + s * 64 + srow8) * K + (kh + scolh);
            __builtin_amdgcn_global_load_lds(AS1C(g),
                AS3(Lc + buf * 65536 + s * 8192 + wave * 1024), 16, 0, 0);
        }
        #pragma unroll
        for (int s = 0; s < 4; ++s) {
            const unsigned short* g = BT + (size_t)(bcol + s * 64 + srow8) * K + (kh + scolh);
            __builtin_amdgcn_global_load_lds(AS1C(g),
                AS3(Lc + buf * 65536 + 32768 + s * 8192 + wave * 1024), 16, 0, 0);
        }
    };

    // prologue: stage tiles 0 and 1
    STAGE(0, 0);
    STAGE(1, 1);
    asm volatile("s_waitcnt vmcnt(8)" ::: "memory");   // tile 0 landed
    __builtin_amdgcn_s_barrier();

    for (int kt = 0; kt < NT; ++kt) {
        const int cur = kt & 1;
        const int abase = cur * 32768;           // hw offset of A region
        const int bbase = cur * 32768 + 16384;   // hw offset of B region

        // B fragments: 4 n x 2 ksub
        bf16x8 bfr[4][2];
        #pragma unroll
        for (int n = 0; n < 4; ++n) {
            const int rb = wc * 64 + n * 16 + fr;
            #pragma unroll
            for (int ks = 0; ks < 2; ++ks) {
                const int ch = (ks * 4 + fq) ^ swz;
                bfr[n][ks] = *(const bf16x8*)&lds[bbase + rb * 64 + ch * 8];
            }
        }
        __builtin_amdgcn_s_setprio(1);
        #pragma unroll
        for (int m = 0; m < 8; ++m) {
            const int ra = wr * 128 + m * 16 + fr;
            const bf16x8 a0 = *(const bf16x8*)&lds[abase + ra * 64 + ((fq ^ swz) * 8)];
            const bf16x8 a1 = *(const bf16x8*)&lds[abase + ra * 64 + (((4 + fq) ^ swz) * 8)];
            #pragma unroll
            for (int n = 0; n < 4; ++n)
                acc[m][n] = __builtin_amdgcn_mfma_f32_16x16x32_bf16(a0, bfr[n][0], acc[m][n], 0, 0, 0);
            #pragma unroll
            for (int n = 0; n < 4; ++n)
                acc[m][n] = __builtin_amdgcn_mfma_f32_16x16x32_bf16(a1, bfr[n][1], acc[m][n], 0, 0, 0);
        }
        __builtin_amdgcn_s_setprio(0);

        if (kt == NT - 1) break;

        asm volatile("s_waitcnt lgkmcnt(0)" ::: "memory");
        __builtin_amdgcn_s_barrier();            // all waves done reading buf[cur]
        if (kt + 2 < NT) {
            STAGE(cur, kt + 2);                  // overwrite freed buffer
            asm volatile("s_waitcnt vmcnt(8)" ::: "memory");  // tile kt+1 landed (8 in flight)
        } else {
            asm volatile("s_waitcnt vmcnt(0)" ::: "memory");  // drain tail
        }
        __builtin_amdgcn_s_barrier();            // collective: tile kt+1 visible to all
    }

    // epilogue: C/D col=lane&15, row=(lane>>4)*4+reg  [HW-verified rounds 8/9]
    #pragma unroll
    for (int m = 0; m < 8; ++m) {
        #pragma unroll
        for (int n = 0; n < 4; ++n) {
            #pragma unroll
            for (int r = 0; r < 4; ++r) {
                const int row = brow + wr * 128 + m * 16 + fq * 4 + r;
                const int col = bcol + wc * 64 + n * 16 + fr;
                float v = acc[m][n][r] + bias[col];
                if (MODE == 0) v = 0.5f * v * (1.0f + erff(v * 0.70710678118654752f));
                const size_t idx = (size_t)bz * M * N + (size_t)row * N + col;
                if (OBF) ((unsigned short*)OutV)[idx] = f32_to_bf16_rne(v);
                else     ((float*)OutV)[idx] = v;
            }
        }
    }
}

extern "C" void kernel_launch(void* const* d_in, const int* in_sizes, int n_in,
                              void* d_out, int out_size, void* d_ws, size_t ws_size,
                              hipStream_t stream)
{
    const float* x         = (const float*)d_in[0];
    const int*   stage_ids = (const int*)d_in[1];
    const int*   view_ids  = (const int*)d_in[2];
    const float* stage_emb = (const float*)d_in[3];
    const float* view_emb  = (const float*)d_in[4];
    const float* rw1       = (const float*)d_in[5];
    const float* rb1       = (const float*)d_in[6];
    const float* rw2       = (const float*)d_in[7];
    const float* rb2       = (const float*)d_in[8];
    const float* w1        = (const float*)d_in[9];
    const float* b1        = (const float*)d_in[10];
    const float* w2        = (const float*)d_in[11];
    const float* b2        = (const float*)d_in[12];

    float* out_f = (float*)d_out;
    const size_t OUT_ELEMS = (size_t)BATCH * TSEQ * DMODEL;

    // ws layout: [4KB hdr][x_bf 64MB][w1T 64MB][w2T 64MB][h grp*8MB]
    const size_t MB64 = 67108864ull;
    char* ws = (char*)d_ws;
    int* sel_ws            = (int*)ws;
    unsigned short* x_bf   = (unsigned short*)(ws + 4096);
    unsigned short* w1T    = (unsigned short*)(ws + 4096 + MB64);
    unsigned short* w2T    = (unsigned short*)(ws + 4096 + 2 * MB64);
    unsigned short* h_bf   = (unsigned short*)(ws + 4096 + 3 * MB64);

    int grp = 1;
    {
        const size_t base = 4096 + 3 * MB64;
        const size_t avail = ws_size > base ? ws_size - base : 0;
        for (int g = 32; g >= 1; g >>= 1) {
            if ((size_t)g * TSEQ * FFFN * 2 <= avail) { grp = g; break; }
        }
    }

    router_r10<<<1, RHID, 0, stream>>>(stage_ids, view_ids, stage_emb, view_emb,
        rw1, rb1, rw2, rb2,
        out_f + OUT_ELEMS,
        out_f + OUT_ELEMS + BATCH * KEXP,
        out_f + OUT_ELEMS + BATCH * KEXP + BATCH,
        sel_ws);

    cvt_f32_bf16_r10<<<2048, 256, 0, stream>>>(x, x_bf, (size_t)BATCH * TSEQ * DMODEL);
    dim3 tb(32, 8);
    transpose_f32_bf16_r10<<<dim3(FFFN / 32, DMODEL / 32, KEXP), tb, 0, stream>>>(w1, w1T, DMODEL, FFFN);
    transpose_f32_bf16_r10<<<dim3(DMODEL / 32, FFFN / 32, KEXP), tb, 0, stream>>>(w2, w2T, FFFN, DMODEL);

    for (int g0 = 0; g0 < BATCH; g0 += grp) {
        // h = gelu(x @ w1[e]^T + b1[e]) : M=1024, N=4096, K=1024 -> bf16
        gemm_bt_r10<0, 1><<<dim3(FFFN / 256, TSEQ / 256, grp), 512, 0, stream>>>(
            x_bf + (size_t)g0 * TSEQ * DMODEL, w1T, b1,
            (void*)h_bf, sel_ws, g0, TSEQ, FFFN, DMODEL);
        // out = h @ w2[e]^T + b2[e]     : M=1024, N=1024, K=4096 -> f32
        gemm_bt_r10<1, 0><<<dim3(DMODEL / 256, TSEQ / 256, grp), 512, 0, stream>>>(
            h_bf, w2T, b2,
            (void*)(out_f + (size_t)g0 * TSEQ * DMODEL), sel_ws, g0, TSEQ, DMODEL, FFFN);
    }
}

// Round 11
// 1033.141 us; speedup vs baseline: 1.6539x; 1.0169x over previous
//
#include <hip/hip_runtime.h>
#include <hip/hip_bf16.h>
#include <math.h>

#define BATCH 32
#define TSEQ 1024
#define DMODEL 1024
#define KEXP 8
#define FFFN 4096
#define EEMB 64
#define RHID 128
#define NSTAGE 5
#define NVIEW 4

typedef float f32x4 __attribute__((ext_vector_type(4)));
typedef __bf16 bf16x8 __attribute__((ext_vector_type(8)));

#define AS1C(p) ((const __attribute__((address_space(1))) unsigned int*)(p))
#define AS3(p)  ((__attribute__((address_space(3))) unsigned int*)(p))

__device__ __forceinline__ unsigned short f32_to_bf16_rne(float f) {
    union { float f; unsigned int u; } v; v.f = f;
    unsigned int u = v.u;
    unsigned int r = u + 0x7FFFu + ((u >> 16) & 1u);
    return (unsigned short)(r >> 16);
}

__device__ void resolve_ids_r11(const int* __restrict__ raw, int* __restrict__ out, int hi) {
    bool is64 = true;
    for (int i = 1; i < 32; i += 2) is64 = is64 && (raw[i] == 0);
    for (int i = 0; i < 32; i += 2) is64 = is64 && (raw[i] >= 0 && raw[i] < hi);
    for (int b = 0; b < BATCH; ++b) {
        int v = is64 ? raw[2 * b] : raw[b];
        v = v < 0 ? 0 : (v >= hi ? hi - 1 : v);
        out[b] = v;
    }
}

// ---------------- router: fp64 exact, f32 outputs ----------------
__global__ void router_r11(const int* __restrict__ stage_ids,
                           const int* __restrict__ view_ids,
                           const float* __restrict__ stage_emb,
                           const float* __restrict__ view_emb,
                           const float* __restrict__ rw1,
                           const float* __restrict__ rb1,
                           const float* __restrict__ rw2,
                           const float* __restrict__ rb2,
                           float* __restrict__ out_probs,
                           float* __restrict__ out_sel,
                           float* __restrict__ out_loss,
                           int* __restrict__ sel_ws)
{
    __shared__ int sids[BATCH], vids[BATCH];
    __shared__ double z[2 * EEMB];
    __shared__ double h[RHID];
    __shared__ double lg[KEXP];
    __shared__ double Psum[KEXP];
    __shared__ int fcount[KEXP];
    const int t = threadIdx.x;
    if (t == 0) {
        resolve_ids_r11(stage_ids, sids, NSTAGE);
        resolve_ids_r11(view_ids, vids, NVIEW);
    }
    if (t < KEXP) { Psum[t] = 0.0; fcount[t] = 0; }
    __syncthreads();

    for (int b = 0; b < BATCH; ++b) {
        const int sid = sids[b], vid = vids[b];
        if (t < EEMB) z[t] = (double)stage_emb[sid * EEMB + t];
        else          z[t] = (double)view_emb[vid * EEMB + (t - EEMB)];
        __syncthreads();
        double acc = (double)rb1[t];
        for (int i = 0; i < 2 * EEMB; ++i) acc += z[i] * (double)rw1[i * RHID + t];
        h[t] = fmax(acc, 0.0);
        __syncthreads();
        if (t < KEXP) {
            double a = (double)rb2[t];
            for (int i = 0; i < RHID; ++i) a += h[i] * (double)rw2[i * KEXP + t];
            lg[t] = a;
        }
        __syncthreads();
        if (t == 0) {
            double mx = lg[0]; int am = 0;
            for (int k = 1; k < KEXP; ++k) if (lg[k] > mx) { mx = lg[k]; am = k; }
            double p[KEXP]; double den = 0.0;
            for (int k = 0; k < KEXP; ++k) { p[k] = exp(lg[k] - mx); den += p[k]; }
            for (int k = 0; k < KEXP; ++k) {
                double pk = p[k] / den;
                out_probs[b * KEXP + k] = (float)pk;
                Psum[k] += pk;
            }
            out_sel[b] = (float)am;
            sel_ws[b] = am;
            fcount[am] += 1;
        }
        __syncthreads();
    }
    if (t == 0) {
        double loss = 0.0;
        for (int k = 0; k < KEXP; ++k)
            loss += ((double)fcount[k] / (double)BATCH) * (Psum[k] / (double)BATCH);
        out_loss[0] = (float)((double)KEXP * loss);
    }
}

// ---------------- prep: f32 -> bf16 convert (x) ----------------
__global__ void cvt_f32_bf16_r11(const float* __restrict__ src,
                                 unsigned short* __restrict__ dst, size_t n)
{
    size_t i = (size_t)blockIdx.x * blockDim.x + threadIdx.x;
    size_t stride = (size_t)gridDim.x * blockDim.x;
    for (size_t j = i * 4; j < n; j += stride * 4) {
        float4 v = *(const float4*)(src + j);
        ushort4 o;
        o.x = f32_to_bf16_rne(v.x); o.y = f32_to_bf16_rne(v.y);
        o.z = f32_to_bf16_rne(v.z); o.w = f32_to_bf16_rne(v.w);
        *(ushort4*)(dst + j) = o;
    }
}

// ------ prep: tiled transpose+convert src[e][R][C] f32 -> dst[e][C][R] bf16 ------
__global__ void transpose_f32_bf16_r11(const float* __restrict__ src,
                                       unsigned short* __restrict__ dst,
                                       int R, int C)
{
    __shared__ float tile[32][33];
    const int e = blockIdx.z;
    const float* s = src + (size_t)e * R * C;
    unsigned short* d = dst + (size_t)e * R * C;
    const int c0 = blockIdx.x * 32, r0 = blockIdx.y * 32;
    const int tx = threadIdx.x, ty = threadIdx.y; // (32, 8)
    #pragma unroll
    for (int i = 0; i < 32; i += 8)
        tile[ty + i][tx] = s[(size_t)(r0 + ty + i) * C + (c0 + tx)];
    __syncthreads();
    #pragma unroll
    for (int i = 0; i < 32; i += 8)
        d[(size_t)(c0 + ty + i) * R + (r0 + tx)] = f32_to_bf16_rne(tile[tx][ty + i]);
}

// ======== 256x256 / BK=32 / 3-buffer / counted-vmcnt / 1-barrier-per-tile GEMM ========
// C = A @ BT^T (+bias [,gelu]).  A: [z][M][K] bf16, BT: [KEXP][N][K] bf16.
// LDS 96KB = 3 buf x (A 16KB + B 16KB); rows 64B (32 hw, 4 chunks of 16B).
// Swizzle: lds chunk = q ^ (row&3) (self-inverse); staging keeps linear dest +
// pre-swizzled global source (rule #21). Stage kt+2 issued at TOP of iter kt
// (hides HBM latency under compute); vmcnt(4) waits only tile kt+1; ONE barrier
// per K-tile; sched_barrier(0) pins reads below the barrier.

template<int MODE, int OBF>  // MODE 0: gelu(acc+bias); 1: acc+bias. OBF: 1 bf16 out, 0 f32 out
__global__ __launch_bounds__(512, 2) void gemm_bt_r11(
    const unsigned short* __restrict__ Aall,
    const unsigned short* __restrict__ BTall,
    const float* __restrict__ biasAll,
    void* __restrict__ OutV,
    const int* __restrict__ sel, int g0,
    int M, int N, int K)
{
    const int bz = blockIdx.z;
    int e = sel[g0 + bz];
    e = e < 0 ? 0 : (e >= KEXP ? KEXP - 1 : e);
    const unsigned short* A  = Aall + (size_t)bz * M * K;
    const unsigned short* BT = BTall + (size_t)e * (size_t)N * K;
    const float* bias = biasAll + (size_t)e * N;

    __shared__ __align__(16) unsigned short lds[49152];   // 96 KB
    char* Lc = (char*)lds;

    const int tid  = threadIdx.x;
    const int lane = tid & 63;
    const int wave = tid >> 6;     // 0..7
    const int wr = wave >> 2;      // 0..1 : 128 output rows each
    const int wc = wave & 3;       // 0..3 : 64 output cols each
    const int fr = lane & 15;
    const int fq = lane >> 4;

    const int brow = blockIdx.y * 256;
    const int bcol = blockIdx.x * 256;

    // staging: gload g covers rows [g*16, g*16+16), 1KB linear dest.
    // lane: row g*16 + (lane>>2), dest chunk lane&3; source chunk pre-swizzled.
    const int srow = lane >> 2;                                  // 0..15
    const int scol = (((lane & 3) ^ ((lane >> 2) & 3))) * 8;     // halfwords

    const int NT = K >> 5;

    const f32x4 zero = {0.f, 0.f, 0.f, 0.f};
    f32x4 acc[8][4];
    #pragma unroll
    for (int m = 0; m < 8; ++m)
        #pragma unroll
        for (int n = 0; n < 4; ++n) acc[m][n] = zero;

    auto STAGE = [&](int buf, int kt) {
        const int kh = kt * 32;
        #pragma unroll
        for (int p = 0; p < 2; ++p) {
            const int g = wave * 2 + p;
            const unsigned short* gA = A + (size_t)(brow + g * 16 + srow) * K + (kh + scol);
            __builtin_amdgcn_global_load_lds(AS1C(gA), AS3(Lc + buf * 32768 + g * 1024), 16, 0, 0);
            const unsigned short* gB = BT + (size_t)(bcol + g * 16 + srow) * K + (kh + scol);
            __builtin_amdgcn_global_load_lds(AS1C(gB), AS3(Lc + buf * 32768 + 16384 + g * 1024), 16, 0, 0);
        }
    };

    // prologue: tiles 0,1 in flight; wait tile 0 (8 outstanding -> 4)
    STAGE(0, 0);
    STAGE(1, 1);
    asm volatile("s_waitcnt vmcnt(4)" ::: "memory");
    __builtin_amdgcn_s_barrier();
    __builtin_amdgcn_sched_barrier(0);

    const int coff = (fq ^ (fr & 3)) * 16;   // swizzled chunk byte-offset (invariant)

    int cur = 0, pre = 2;
    for (int kt = 0; kt < NT; ++kt) {
        if (kt + 2 < NT) STAGE(pre, kt + 2);   // issue-early: hides under compute

        const int ab = cur * 32768;
        const int bb = ab + 16384;

        bf16x8 bfr[4];
        #pragma unroll
        for (int n = 0; n < 4; ++n) {
            const int rb = wc * 64 + n * 16 + fr;
            bfr[n] = *(const bf16x8*)(Lc + bb + rb * 64 + coff);
        }
        __builtin_amdgcn_s_setprio(1);
        #pragma unroll
        for (int m = 0; m < 8; ++m) {
            const int ra = wr * 128 + m * 16 + fr;
            const bf16x8 af = *(const bf16x8*)(Lc + ab + ra * 64 + coff);
            #pragma unroll
            for (int n = 0; n < 4; ++n)
                acc[m][n] = __builtin_amdgcn_mfma_f32_16x16x32_bf16(af, bfr[n], acc[m][n], 0, 0, 0);
        }
        __builtin_amdgcn_s_setprio(0);

        if (kt == NT - 1) break;
        if (kt + 2 < NT) asm volatile("s_waitcnt vmcnt(4)" ::: "memory");  // tile kt+1 landed
        else             asm volatile("s_waitcnt vmcnt(0)" ::: "memory");  // tail drain
        __builtin_amdgcn_s_barrier();            // tile kt+1 visible; buf (kt+2)%3 free
        __builtin_amdgcn_sched_barrier(0);       // no read hoisting above barrier
        cur = cur == 2 ? 0 : cur + 1;
        pre = pre == 2 ? 0 : pre + 1;
    }

    // epilogue: C/D col=lane&15, row=(lane>>4)*4+reg  [HW-verified rounds 8-10]
    #pragma unroll
    for (int m = 0; m < 8; ++m) {
        #pragma unroll
        for (int n = 0; n < 4; ++n) {
            #pragma unroll
            for (int r = 0; r < 4; ++r) {
                const int row = brow + wr * 128 + m * 16 + fq * 4 + r;
                const int col = bcol + wc * 64 + n * 16 + fr;
                float v = acc[m][n][r] + bias[col];
                if (MODE == 0) v = 0.5f * v * (1.0f + erff(v * 0.70710678118654752f));
                const size_t idx = (size_t)bz * M * N + (size_t)row * N + col;
                if (OBF) ((unsigned short*)OutV)[idx] = f32_to_bf16_rne(v);
                else     ((float*)OutV)[idx] = v;
            }
        }
    }
}

extern "C" void kernel_launch(void* const* d_in, const int* in_sizes, int n_in,
                              void* d_out, int out_size, void* d_ws, size_t ws_size,
                              hipStream_t stream)
{
    const float* x         = (const float*)d_in[0];
    const int*   stage_ids = (const int*)d_in[1];
    const int*   view_ids  = (const int*)d_in[2];
    const float* stage_emb = (const float*)d_in[3];
    const float* view_emb  = (const float*)d_in[4];
    const float* rw1       = (const float*)d_in[5];
    const float* rb1       = (const float*)d_in[6];
    const float* rw2       = (const float*)d_in[7];
    const float* rb2       = (const float*)d_in[8];
    const float* w1        = (const float*)d_in[9];
    const float* b1        = (const float*)d_in[10];
    const float* w2        = (const float*)d_in[11];
    const float* b2        = (const float*)d_in[12];

    float* out_f = (float*)d_out;
    const size_t OUT_ELEMS = (size_t)BATCH * TSEQ * DMODEL;

    // ws layout: [4KB hdr][x_bf 64MB][w1T 64MB][w2T 64MB][h grp*8MB]
    const size_t MB64 = 67108864ull;
    char* ws = (char*)d_ws;
    int* sel_ws            = (int*)ws;
    unsigned short* x_bf   = (unsigned short*)(ws + 4096);
    unsigned short* w1T    = (unsigned short*)(ws + 4096 + MB64);
    unsigned short* w2T    = (unsigned short*)(ws + 4096 + 2 * MB64);
    unsigned short* h_bf   = (unsigned short*)(ws + 4096 + 3 * MB64);

    int grp = 1;
    {
        const size_t base = 4096 + 3 * MB64;
        const size_t avail = ws_size > base ? ws_size - base : 0;
        for (int g = 32; g >= 1; g >>= 1) {
            if ((size_t)g * TSEQ * FFFN * 2 <= avail) { grp = g; break; }
        }
    }

    router_r11<<<1, RHID, 0, stream>>>(stage_ids, view_ids, stage_emb, view_emb,
        rw1, rb1, rw2, rb2,
        out_f + OUT_ELEMS,
        out_f + OUT_ELEMS + BATCH * KEXP,
        out_f + OUT_ELEMS + BATCH * KEXP + BATCH,
        sel_ws);

    cvt_f32_bf16_r11<<<2048, 256, 0, stream>>>(x, x_bf, (size_t)BATCH * TSEQ * DMODEL);
    dim3 tb(32, 8);
    transpose_f32_bf16_r11<<<dim3(FFFN / 32, DMODEL / 32, KEXP), tb, 0, stream>>>(w1, w1T, DMODEL, FFFN);
    transpose_f32_bf16_r11<<<dim3(DMODEL / 32, FFFN / 32, KEXP), tb, 0, stream>>>(w2, w2T, FFFN, DMODEL);

    for (int g0 = 0; g0 < BATCH; g0 += grp) {
        // h = gelu(x @ w1[e]^T + b1[e]) : M=1024, N=4096, K=1024 -> bf16
        gemm_bt_r11<0, 1><<<dim3(FFFN / 256, TSEQ / 256, grp), 512, 0, stream>>>(
            x_bf + (size_t)g0 * TSEQ * DMODEL, w1T, b1,
            (void*)h_bf, sel_ws, g0, TSEQ, FFFN, DMODEL);
        // out = h @ w2[e]^T + b2[e]     : M=1024, N=1024, K=4096 -> f32
        gemm_bt_r11<1, 0><<<dim3(DMODEL / 256, TSEQ / 256, grp), 512, 0, stream>>>(
            h_bf, w2T, b2,
            (void*)(out_f + (size_t)g0 * TSEQ * DMODEL), sel_ws, g0, TSEQ, DMODEL, FFFN);
    }
}

// Round 12
// 1025.099 us; speedup vs baseline: 1.6669x; 1.0078x over previous
//
#include <hip/hip_runtime.h>
#include <hip/hip_bf16.h>
#include <math.h>

#define BATCH 32
#define TSEQ 1024
#define DMODEL 1024
#define KEXP 8
#define FFFN 4096
#define EEMB 64
#define RHID 128
#define NSTAGE 5
#define NVIEW 4

typedef float f32x4 __attribute__((ext_vector_type(4)));
typedef __bf16 bf16x8 __attribute__((ext_vector_type(8)));

#define AS1C(p) ((const __attribute__((address_space(1))) unsigned int*)(p))
#define AS3(p)  ((__attribute__((address_space(3))) unsigned int*)(p))

__device__ __forceinline__ unsigned short f32_to_bf16_rne(float f) {
    union { float f; unsigned int u; } v; v.f = f;
    unsigned int u = v.u;
    unsigned int r = u + 0x7FFFu + ((u >> 16) & 1u);
    return (unsigned short)(r >> 16);
}

__device__ void resolve_ids_r12(const int* __restrict__ raw, int* __restrict__ out, int hi) {
    bool is64 = true;
    for (int i = 1; i < 32; i += 2) is64 = is64 && (raw[i] == 0);
    for (int i = 0; i < 32; i += 2) is64 = is64 && (raw[i] >= 0 && raw[i] < hi);
    for (int b = 0; b < BATCH; ++b) {
        int v = is64 ? raw[2 * b] : raw[b];
        v = v < 0 ? 0 : (v >= hi ? hi - 1 : v);
        out[b] = v;
    }
}

// ---------------- router: fp64 exact, f32 outputs ----------------
__global__ void router_r12(const int* __restrict__ stage_ids,
                           const int* __restrict__ view_ids,
                           const float* __restrict__ stage_emb,
                           const float* __restrict__ view_emb,
                           const float* __restrict__ rw1,
                           const float* __restrict__ rb1,
                           const float* __restrict__ rw2,
                           const float* __restrict__ rb2,
                           float* __restrict__ out_probs,
                           float* __restrict__ out_sel,
                           float* __restrict__ out_loss,
                           int* __restrict__ sel_ws)
{
    __shared__ int sids[BATCH], vids[BATCH];
    __shared__ double z[2 * EEMB];
    __shared__ double h[RHID];
    __shared__ double lg[KEXP];
    __shared__ double Psum[KEXP];
    __shared__ int fcount[KEXP];
    const int t = threadIdx.x;
    if (t == 0) {
        resolve_ids_r12(stage_ids, sids, NSTAGE);
        resolve_ids_r12(view_ids, vids, NVIEW);
    }
    if (t < KEXP) { Psum[t] = 0.0; fcount[t] = 0; }
    __syncthreads();

    for (int b = 0; b < BATCH; ++b) {
        const int sid = sids[b], vid = vids[b];
        if (t < EEMB) z[t] = (double)stage_emb[sid * EEMB + t];
        else          z[t] = (double)view_emb[vid * EEMB + (t - EEMB)];
        __syncthreads();
        double acc = (double)rb1[t];
        for (int i = 0; i < 2 * EEMB; ++i) acc += z[i] * (double)rw1[i * RHID + t];
        h[t] = fmax(acc, 0.0);
        __syncthreads();
        if (t < KEXP) {
            double a = (double)rb2[t];
            for (int i = 0; i < RHID; ++i) a += h[i] * (double)rw2[i * KEXP + t];
            lg[t] = a;
        }
        __syncthreads();
        if (t == 0) {
            double mx = lg[0]; int am = 0;
            for (int k = 1; k < KEXP; ++k) if (lg[k] > mx) { mx = lg[k]; am = k; }
            double p[KEXP]; double den = 0.0;
            for (int k = 0; k < KEXP; ++k) { p[k] = exp(lg[k] - mx); den += p[k]; }
            for (int k = 0; k < KEXP; ++k) {
                double pk = p[k] / den;
                out_probs[b * KEXP + k] = (float)pk;
                Psum[k] += pk;
            }
            out_sel[b] = (float)am;
            sel_ws[b] = am;
            fcount[am] += 1;
        }
        __syncthreads();
    }
    if (t == 0) {
        double loss = 0.0;
        for (int k = 0; k < KEXP; ++k)
            loss += ((double)fcount[k] / (double)BATCH) * (Psum[k] / (double)BATCH);
        out_loss[0] = (float)((double)KEXP * loss);
    }
}

// ---------------- prep: f32 -> bf16 convert (x) ----------------
__global__ void cvt_f32_bf16_r12(const float* __restrict__ src,
                                 unsigned short* __restrict__ dst, size_t n)
{
    size_t i = (size_t)blockIdx.x * blockDim.x + threadIdx.x;
    size_t stride = (size_t)gridDim.x * blockDim.x;
    for (size_t j = i * 4; j < n; j += stride * 4) {
        float4 v = *(const float4*)(src + j);
        ushort4 o;
        o.x = f32_to_bf16_rne(v.x); o.y = f32_to_bf16_rne(v.y);
        o.z = f32_to_bf16_rne(v.z); o.w = f32_to_bf16_rne(v.w);
        *(ushort4*)(dst + j) = o;
    }
}

// ------ prep: tiled transpose+convert src[e][R][C] f32 -> dst[e][C][R] bf16 ------
__global__ void transpose_f32_bf16_r12(const float* __restrict__ src,
                                       unsigned short* __restrict__ dst,
                                       int R, int C)
{
    __shared__ float tile[32][33];
    const int e = blockIdx.z;
    const float* s = src + (size_t)e * R * C;
    unsigned short* d = dst + (size_t)e * R * C;
    const int c0 = blockIdx.x * 32, r0 = blockIdx.y * 32;
    const int tx = threadIdx.x, ty = threadIdx.y; // (32, 8)
    #pragma unroll
    for (int i = 0; i < 32; i += 8)
        tile[ty + i][tx] = s[(size_t)(r0 + ty + i) * C + (c0 + tx)];
    __syncthreads();
    #pragma unroll
    for (int i = 0; i < 32; i += 8)
        d[(size_t)(c0 + ty + i) * R + (r0 + tx)] = f32_to_bf16_rne(tile[tx][ty + i]);
}

// ==== 256x256 / BK=32 / 4-buffer / 2-fine-phases-per-tile / counted-vmcnt GEMM ====
// C = A @ BT^T (+bias [,gelu]).  A: [z][M][K] bf16, BT: [KEXP][N][K] bf16.
// LDS 128KB = 4 buf x (A 16KB + B 16KB); rows 64B (4 chunks of 16B).
// Swizzle (corrected): read chunk = fq ^ ((fr>>1)&3); staging source chunk =
// (lane&3) ^ ((lane>>3)&3); linear gload_lds dest (rule #21). Each K-tile:
// 2 phases of {ds_read subset || stage half of tile kt+2} -> bar -> lgkm(0) ->
// 16 MFMA -> bar. vmcnt(4) once per tile (4 gloads/wave/tile in flight per tile).

template<int MODE, int OBF>  // MODE 0: gelu(acc+bias); 1: acc+bias. OBF: 1 bf16 out, 0 f32 out
__global__ __launch_bounds__(512, 2) void gemm_bt_r12(
    const unsigned short* __restrict__ Aall,
    const unsigned short* __restrict__ BTall,
    const float* __restrict__ biasAll,
    void* __restrict__ OutV,
    const int* __restrict__ sel, int g0,
    int M, int N, int K)
{
    const int bz = blockIdx.z;
    int e = sel[g0 + bz];
    e = e < 0 ? 0 : (e >= KEXP ? KEXP - 1 : e);
    const unsigned short* A  = Aall + (size_t)bz * M * K;
    const unsigned short* BT = BTall + (size_t)e * (size_t)N * K;
    const float* bias = biasAll + (size_t)e * N;

    __shared__ __align__(16) unsigned short lds[65536];   // 128 KB
    char* Lc = (char*)lds;

    const int tid  = threadIdx.x;
    const int lane = tid & 63;
    const int wave = tid >> 6;     // 0..7
    const int wr = wave >> 2;      // 0..1 : 128 output rows each
    const int wc = wave & 3;       // 0..3 : 64 output cols each
    const int fr = lane & 15;
    const int fq = lane >> 4;

    const int brow = blockIdx.y * 256;
    const int bcol = blockIdx.x * 256;

    // staging: each gload = 1KB = 16 rows of 64B; lane -> row lane>>2, chunk lane&3
    const int srow = lane >> 2;                                 // 0..15
    const int scol = ((lane & 3) ^ ((lane >> 3) & 3)) * 8;      // pre-swizzled halfwords
    // ds-read swizzled chunk byte offset (row&~1 parity-free spread)
    const int coff = (fq ^ ((fr >> 1) & 3)) * 16;

    const int NT = K >> 5;

    const f32x4 zero = {0.f, 0.f, 0.f, 0.f};
    f32x4 acc[8][4];
    #pragma unroll
    for (int m = 0; m < 8; ++m)
        #pragma unroll
        for (int n = 0; n < 4; ++n) acc[m][n] = zero;

    // stage one half (p=0/1) of tile kt into buffer buf: 1 A-gload + 1 B-gload
    auto STAGE_H = [&](int buf, int kt, int p) {
        const int kh = kt * 32;
        const int g = wave * 2 + p;   // 0..15: rows [g*16, g*16+16)
        const unsigned short* gA = A + (size_t)(brow + g * 16 + srow) * K + (kh + scol);
        __builtin_amdgcn_global_load_lds(AS1C(gA), AS3(Lc + buf * 32768 + g * 1024), 16, 0, 0);
        const unsigned short* gB = BT + (size_t)(bcol + g * 16 + srow) * K + (kh + scol);
        __builtin_amdgcn_global_load_lds(AS1C(gB), AS3(Lc + buf * 32768 + 16384 + g * 1024), 16, 0, 0);
    };

    // prologue: tiles 0,1 staged; wait tile 0 (8 outstanding -> keep 4)
    STAGE_H(0, 0, 0); STAGE_H(0, 0, 1);
    STAGE_H(1, 1, 0); STAGE_H(1, 1, 1);
    asm volatile("s_waitcnt vmcnt(4)" ::: "memory");
    __builtin_amdgcn_s_barrier();

    for (int kt = 0; kt < NT; ++kt) {
        const int cur = kt & 3;
        const int nxt = (kt + 2) & 3;
        const int ab = cur * 32768;
        const int bb = ab + 16384;
        const bool pf = (kt + 2) < NT;

        // ======== phase 0: read B[4] + A[m0..3]; stage half 0 of kt+2 ========
        bf16x8 bfr[4], af[4];
        #pragma unroll
        for (int n = 0; n < 4; ++n) {
            const int rb = wc * 64 + n * 16 + fr;
            bfr[n] = *(const bf16x8*)(Lc + bb + rb * 64 + coff);
        }
        #pragma unroll
        for (int m = 0; m < 4; ++m) {
            const int ra = wr * 128 + m * 16 + fr;
            af[m] = *(const bf16x8*)(Lc + ab + ra * 64 + coff);
        }
        if (pf) STAGE_H(nxt, kt + 2, 0);
        __builtin_amdgcn_s_barrier();
        asm volatile("s_waitcnt lgkmcnt(0)" ::: "memory");
        __builtin_amdgcn_sched_barrier(0);
        __builtin_amdgcn_s_setprio(1);
        #pragma unroll
        for (int m = 0; m < 4; ++m)
            #pragma unroll
            for (int n = 0; n < 4; ++n)
                acc[m][n] = __builtin_amdgcn_mfma_f32_16x16x32_bf16(af[m], bfr[n], acc[m][n], 0, 0, 0);
        __builtin_amdgcn_s_setprio(0);
        __builtin_amdgcn_s_barrier();

        // ======== phase 1: read A[m4..7]; stage half 1 of kt+2; tile-end vmcnt ========
        bf16x8 ag[4];
        #pragma unroll
        for (int m = 0; m < 4; ++m) {
            const int ra = wr * 128 + (m + 4) * 16 + fr;
            ag[m] = *(const bf16x8*)(Lc + ab + ra * 64 + coff);
        }
        if (pf) STAGE_H(nxt, kt + 2, 1);
        if (kt < NT - 1) {
            if (pf) asm volatile("s_waitcnt vmcnt(4)" ::: "memory");  // tile kt+1 landed
            else    asm volatile("s_waitcnt vmcnt(0)" ::: "memory");  // tail drain
        }
        __builtin_amdgcn_s_barrier();
        asm volatile("s_waitcnt lgkmcnt(0)" ::: "memory");
        __builtin_amdgcn_sched_barrier(0);
        __builtin_amdgcn_s_setprio(1);
        #pragma unroll
        for (int m = 0; m < 4; ++m)
            #pragma unroll
            for (int n = 0; n < 4; ++n)
                acc[m + 4][n] = __builtin_amdgcn_mfma_f32_16x16x32_bf16(ag[m], bfr[n], acc[m + 4][n], 0, 0, 0);
        __builtin_amdgcn_s_setprio(0);
        __builtin_amdgcn_s_barrier();
    }

    // epilogue: C/D col=lane&15, row=(lane>>4)*4+reg  [HW-verified rounds 8-11]
    #pragma unroll
    for (int m = 0; m < 8; ++m) {
        #pragma unroll
        for (int n = 0; n < 4; ++n) {
            #pragma unroll
            for (int r = 0; r < 4; ++r) {
                const int row = brow + wr * 128 + m * 16 + fq * 4 + r;
                const int col = bcol + wc * 64 + n * 16 + fr;
                float v = acc[m][n][r] + bias[col];
                if (MODE == 0) v = 0.5f * v * (1.0f + erff(v * 0.70710678118654752f));
                const size_t idx = (size_t)bz * M * N + (size_t)row * N + col;
                if (OBF) ((unsigned short*)OutV)[idx] = f32_to_bf16_rne(v);
                else     ((float*)OutV)[idx] = v;
            }
        }
    }
}

extern "C" void kernel_launch(void* const* d_in, const int* in_sizes, int n_in,
                              void* d_out, int out_size, void* d_ws, size_t ws_size,
                              hipStream_t stream)
{
    const float* x         = (const float*)d_in[0];
    const int*   stage_ids = (const int*)d_in[1];
    const int*   view_ids  = (const int*)d_in[2];
    const float* stage_emb = (const float*)d_in[3];
    const float* view_emb  = (const float*)d_in[4];
    const float* rw1       = (const float*)d_in[5];
    const float* rb1       = (const float*)d_in[6];
    const float* rw2       = (const float*)d_in[7];
    const float* rb2       = (const float*)d_in[8];
    const float* w1        = (const float*)d_in[9];
    const float* b1        = (const float*)d_in[10];
    const float* w2        = (const float*)d_in[11];
    const float* b2        = (const float*)d_in[12];

    float* out_f = (float*)d_out;
    const size_t OUT_ELEMS = (size_t)BATCH * TSEQ * DMODEL;

    // ws layout: [4KB hdr][x_bf 64MB][w1T 64MB][w2T 64MB][h grp*8MB]
    const size_t MB64 = 67108864ull;
    char* ws = (char*)d_ws;
    int* sel_ws            = (int*)ws;
    unsigned short* x_bf   = (unsigned short*)(ws + 4096);
    unsigned short* w1T    = (unsigned short*)(ws + 4096 + MB64);
    unsigned short* w2T    = (unsigned short*)(ws + 4096 + 2 * MB64);
    unsigned short* h_bf   = (unsigned short*)(ws + 4096 + 3 * MB64);

    int grp = 1;
    {
        const size_t base = 4096 + 3 * MB64;
        const size_t avail = ws_size > base ? ws_size - base : 0;
        for (int g = 32; g >= 1; g >>= 1) {
            if ((size_t)g * TSEQ * FFFN * 2 <= avail) { grp = g; break; }
        }
    }

    router_r12<<<1, RHID, 0, stream>>>(stage_ids, view_ids, stage_emb, view_emb,
        rw1, rb1, rw2, rb2,
        out_f + OUT_ELEMS,
        out_f + OUT_ELEMS + BATCH * KEXP,
        out_f + OUT_ELEMS + BATCH * KEXP + BATCH,
        sel_ws);

    cvt_f32_bf16_r12<<<2048, 256, 0, stream>>>(x, x_bf, (size_t)BATCH * TSEQ * DMODEL);
    dim3 tb(32, 8);
    transpose_f32_bf16_r12<<<dim3(FFFN / 32, DMODEL / 32, KEXP), tb, 0, stream>>>(w1, w1T, DMODEL, FFFN);
    transpose_f32_bf16_r12<<<dim3(DMODEL / 32, FFFN / 32, KEXP), tb, 0, stream>>>(w2, w2T, FFFN, DMODEL);

    for (int g0 = 0; g0 < BATCH; g0 += grp) {
        // h = gelu(x @ w1[e]^T + b1[e]) : M=1024, N=4096, K=1024 -> bf16
        gemm_bt_r12<0, 1><<<dim3(FFFN / 256, TSEQ / 256, grp), 512, 0, stream>>>(
            x_bf + (size_t)g0 * TSEQ * DMODEL, w1T, b1,
            (void*)h_bf, sel_ws, g0, TSEQ, FFFN, DMODEL);
        // out = h @ w2[e]^T + b2[e]     : M=1024, N=1024, K=4096 -> f32
        gemm_bt_r12<1, 0><<<dim3(DMODEL / 256, TSEQ / 256, grp), 512, 0, stream>>>(
            h_bf, w2T, b2,
            (void*)(out_f + (size_t)g0 * TSEQ * DMODEL), sel_ws, g0, TSEQ, DMODEL, FFFN);
    }
}